// Round 1
// baseline (56.647 us; speedup 1.0000x reference)
//
#include <hip/hip_runtime.h>
#include <math.h>

#define NROWS 65536
#define NCLS  1000
#define NV4   250          // float4 chunks per row (1000/4)
#define BLOCKS 2048        // stage-1 grid; 2048*4 waves = 8192 waves, 8 rows/wave
#define WAVES_PER_BLOCK 4

__global__ __launch_bounds__(256) void focal_stage1(
    const float* __restrict__ inp,
    const int*   __restrict__ tgt,
    const float* __restrict__ gamma_t,
    const float* __restrict__ alpha_t,
    float* __restrict__ partial) {

  __shared__ float wsum[WAVES_PER_BLOCK];
  const int lane = threadIdx.x & 63;
  const int wid  = threadIdx.x >> 6;
  const int gw   = blockIdx.x * WAVES_PER_BLOCK + wid;   // global wave id
  const int nw   = gridDim.x * WAVES_PER_BLOCK;

  float acc = 0.0f;

  for (int row = gw; row < NROWS; row += nw) {
    const float4* __restrict__ p =
        reinterpret_cast<const float4*>(inp + (size_t)row * NCLS);
    const int t = tgt[row];

    // ---- load row into registers (up to 4 float4 per lane), lane-local max
    float4 v[4];
    float m = -INFINITY;
#pragma unroll
    for (int k = 0; k < 4; ++k) {
      const int idx = lane + k * 64;
      if (idx < NV4) {
        v[k] = p[idx];
        m = fmaxf(m, fmaxf(fmaxf(v[k].x, v[k].y), fmaxf(v[k].z, v[k].w)));
      }
    }
    // ---- wave max
#pragma unroll
    for (int o = 32; o > 0; o >>= 1) m = fmaxf(m, __shfl_xor(m, o));

    // ---- lane-local sum of exp, and extract x[target]
    float s = 0.0f, xt = 0.0f;
#pragma unroll
    for (int k = 0; k < 4; ++k) {
      const int idx = lane + k * 64;
      if (idx < NV4) {
        s += __expf(v[k].x - m) + __expf(v[k].y - m) +
             __expf(v[k].z - m) + __expf(v[k].w - m);
        const int e = idx * 4;
        xt += (e + 0 == t ? v[k].x : 0.0f) + (e + 1 == t ? v[k].y : 0.0f) +
              (e + 2 == t ? v[k].z : 0.0f) + (e + 3 == t ? v[k].w : 0.0f);
      }
    }
    // ---- wave sum (s and xt together)
#pragma unroll
    for (int o = 32; o > 0; o >>= 1) {
      s  += __shfl_xor(s,  o);
      xt += __shfl_xor(xt, o);
    }

    // ---- focal epilogue (uniform across the wave; lane 0 accumulates)
    if (lane == 0) {
      const float logZ = m + __logf(s);
      const float ce   = logZ - xt;          // -log_softmax at target
      const float pt   = __expf(-ce);
      const float om   = 1.0f - pt;
      const float g    = gamma_t[t];
      const float a    = alpha_t[t];
      // om in [0,1); g in [1,3). __powf(0, g) -> exp(-inf) -> 0, fine.
      acc += a * __powf(om, g) * ce;
    }
  }

  if (lane == 0) wsum[wid] = acc;
  __syncthreads();
  if (threadIdx.x == 0) {
    float b = 0.0f;
#pragma unroll
    for (int w = 0; w < WAVES_PER_BLOCK; ++w) b += wsum[w];
    partial[blockIdx.x] = b;   // every entry written every call -> deterministic
  }
}

__global__ __launch_bounds__(256) void focal_stage2(
    const float* __restrict__ partial, float* __restrict__ out) {
  __shared__ float wsum[4];
  const int lane = threadIdx.x & 63;
  const int wid  = threadIdx.x >> 6;

  float s = 0.0f;
  for (int i = threadIdx.x; i < BLOCKS; i += 256) s += partial[i];
#pragma unroll
  for (int o = 32; o > 0; o >>= 1) s += __shfl_xor(s, o);
  if (lane == 0) wsum[wid] = s;
  __syncthreads();
  if (threadIdx.x == 0) {
    float tot = wsum[0] + wsum[1] + wsum[2] + wsum[3];
    out[0] = tot * (1.0f / (float)NROWS);
  }
}

extern "C" void kernel_launch(void* const* d_in, const int* in_sizes, int n_in,
                              void* d_out, int out_size, void* d_ws, size_t ws_size,
                              hipStream_t stream) {
  const float* inp     = (const float*)d_in[0];
  const int*   tgt     = (const int*)  d_in[1];
  const float* gamma_t = (const float*)d_in[2];
  const float* alpha_t = (const float*)d_in[3];
  float* out     = (float*)d_out;
  float* partial = (float*)d_ws;   // BLOCKS floats of scratch

  focal_stage1<<<BLOCKS, 256, 0, stream>>>(inp, tgt, gamma_t, alpha_t, partial);
  focal_stage2<<<1, 256, 0, stream>>>(partial, out);
}